// Round 10
// baseline (170.463 us; speedup 1.0000x reference)
//
#include <hip/hip_runtime.h>

#define BATCH 2048
#define NTEACH 64

typedef __attribute__((ext_vector_type(8))) short short8;
typedef __attribute__((ext_vector_type(4))) float f32x4;

__device__ __forceinline__ unsigned short f2bf(float f) {
    unsigned u = __float_as_uint(f);
    u += 0x7FFFu + ((u >> 16) & 1u);          // round-to-nearest-even
    return (unsigned short)(u >> 16);
}

__device__ __forceinline__ short8 cvt8(float4 a, float4 b) {
    short8 r;
    r[0] = (short)f2bf(a.x); r[1] = (short)f2bf(a.y);
    r[2] = (short)f2bf(a.z); r[3] = (short)f2bf(a.w);
    r[4] = (short)f2bf(b.x); r[5] = (short)f2bf(b.y);
    r[6] = (short)f2bf(b.z); r[7] = (short)f2bf(b.w);
    return r;
}

// Barrier-free per-wave scan (R8-proven): each wave independently computes the
// stable ranking of teacher-t samples. Returns (start, count), wave-uniform.
__device__ __forceinline__ int2 wave_scan(const int* __restrict__ tidx,
                                          int t, int* ord) {
    const int lane = threadIdx.x & 63;
    int base = 0, lt = 0;
#pragma unroll
    for (int r = 0; r < 32; ++r) {
        int i = r * 64 + lane;
        int v = tidx[i];
        bool f = (v == t);
        lt += (v < t) ? 1 : 0;
        unsigned long long b = __ballot(f);
        if (ord && f) {
            int rank = base + __builtin_popcountll(b & ((1ull << lane) - 1ull));
            ord[rank] = i;
        }
        base += __builtin_popcountll(b);
    }
#pragma unroll
    for (int off = 32; off; off >>= 1) lt += __shfl_down(lt, off);
    lt = __shfl(lt, 0);
    return make_int2(lt, base);
}

// ---------- L0: obs(48) -> h0(512) bf16 sorted, gather + elu ----------
// grid (16,64); waves = N2 x M2. Weight loads issued BEFORE the scan (latency
// hidden under it). Block (0,t) publishes offsets/order and zeroes cnt[t].
// MFMA 16x16x32 bf16 (verified R2-R8): A row=lane&15, k=(lane>>4)*8+j;
// B col=lane&15; D col=lane&15, row=(lane>>4)*4+j.
__global__ __launch_bounds__(256) void l0_kernel(const float* __restrict__ obs,
                                                 const int* __restrict__ tidx,
                                                 const float* __restrict__ w0,
                                                 const float* __restrict__ b0,
                                                 int* __restrict__ offsets_g,
                                                 int* __restrict__ order_g,
                                                 int* __restrict__ cnt_g,
                                                 unsigned short* __restrict__ h0) {
    __shared__ int ord[BATCH];
    const int t = blockIdx.y;
    const int lane = threadIdx.x & 63, wid = threadIdx.x >> 6;
    const int ln = lane & 15, kg = lane >> 4;
    const int nq = wid & 1, mq = wid >> 1;
    const int n0 = blockIdx.x * 32 + nq * 16;

    // issue weight + bias loads first (clamped addresses, masked later)
    const float* wr = w0 + ((size_t)t * 512 + n0 + ln) * 48;
    bool wvalid[2];
    float4 wa[2], wb[2];
#pragma unroll
    for (int kt = 0; kt < 2; ++kt) {
        int kb = kt * 32 + kg * 8;
        wvalid[kt] = kb < 48;
        const float* p = wr + (wvalid[kt] ? kb : 0);
        wa[kt] = *(const float4*)p;
        wb[kt] = *(const float4*)(p + 4);
    }
    const float bias = b0[(size_t)t * 512 + n0 + ln];

    int2 sc = wave_scan(tidx, t, ord);
    const int start = sc.x, count = sc.y;

    if (blockIdx.x == 0) {
        if (threadIdx.x == 0) {
            offsets_g[t] = start;
            if (t == 0) offsets_g[NTEACH] = BATCH;
            cnt_g[t] = 0;                      // fan-in counter for l1f
        }
        for (int i = threadIdx.x; i < count; i += 256) order_g[start + i] = ord[i];
    }
    if (count == 0) return;

    short8 bf[2];
#pragma unroll
    for (int kt = 0; kt < 2; ++kt) {
        short8 z = {0, 0, 0, 0, 0, 0, 0, 0};
        bf[kt] = wvalid[kt] ? cvt8(wa[kt], wb[kt]) : z;
    }

    for (int r0 = mq * 16; r0 < count; r0 += 32) {
        int lr = r0 + ln;
        const float* xr = obs + (size_t)ord[lr < count ? lr : 0] * 48;
        short8 af[2];
#pragma unroll
        for (int kt = 0; kt < 2; ++kt) {
            int kb = kt * 32 + kg * 8;
            short8 f8 = {0, 0, 0, 0, 0, 0, 0, 0};
            if (kb < 48)
                f8 = cvt8(*(const float4*)(xr + kb), *(const float4*)(xr + kb + 4));
            af[kt] = f8;
        }
        f32x4 acc = {0.f, 0.f, 0.f, 0.f};
        acc = __builtin_amdgcn_mfma_f32_16x16x32_bf16(af[0], bf[0], acc, 0, 0, 0);
        acc = __builtin_amdgcn_mfma_f32_16x16x32_bf16(af[1], bf[1], acc, 0, 0, 0);
#pragma unroll
        for (int j = 0; j < 4; ++j) {
            int row = r0 + kg * 4 + j;
            if (row < count) {
                float v = acc[j] + bias;
                v = v > 0.f ? v : expm1f(v);
                h0[(size_t)(start + row) * 512 + n0 + ln] = f2bf(v);
            }
        }
    }
}

// ---------- L1 + fan-in(L2 + final) ----------
// grid (16,64): block = 16-col h1 slice of teacher t; waves = K4 (w2 read
// once). After storing its slice each block does threadfence+atomicAdd; the
// 16th (last) block of teacher t — all h1 published — runs L2+final for the
// whole teacher (w4/w6 read exactly once, overlapped with other teachers' L1).
__global__ __launch_bounds__(256, 4) void l1f_kernel(
    const unsigned short* __restrict__ h0, const int* __restrict__ offsets_g,
    const int* __restrict__ order_g, int* __restrict__ cnt_g,
    const float* __restrict__ w2, const float* __restrict__ b2,
    const float* __restrict__ w4, const float* __restrict__ b4,
    const float* __restrict__ w6, const float* __restrict__ b6,
    unsigned short* __restrict__ h1, float* __restrict__ out) {
    __shared__ f32x4 red[3][64];
    __shared__ char h2b[32768];           // up to 128 rows x 128 cols bf16, swizzled
    __shared__ int done_s;

    const int t = blockIdx.y;
    const int start = offsets_g[t];
    const int count = offsets_g[t + 1] - start;
    if (count == 0) return;
    const int lane = threadIdx.x & 63, wid = threadIdx.x >> 6;
    const int ln = lane & 15, kg = lane >> 4;

    // ---------------- L1 slice: 16 cols, K4 wave split ----------------
    {
        const int n0 = blockIdx.x * 16;
        const int kbase = wid * 128;
        short8 bf[4];
        const float* wr = w2 + ((size_t)t * 256 + n0 + ln) * 512 + kbase;
#pragma unroll
        for (int k8 = 0; k8 < 4; ++k8) {
            int kb = k8 * 32 + kg * 8;
            bf[k8] = cvt8(*(const float4*)(wr + kb), *(const float4*)(wr + kb + 4));
        }
        const float bias = b2[(size_t)t * 256 + n0 + ln];
        for (int r0 = 0; r0 < count; r0 += 16) {
            const unsigned short* xr =
                h0 + (size_t)(start + r0 + ln) * 512 + kbase + kg * 8;
            f32x4 acc = {0.f, 0.f, 0.f, 0.f};
#pragma unroll
            for (int k8 = 0; k8 < 4; ++k8)
                acc = __builtin_amdgcn_mfma_f32_16x16x32_bf16(
                    *(const short8*)(xr + k8 * 32), bf[k8], acc, 0, 0, 0);
            __syncthreads();
            if (wid > 0) red[wid - 1][lane] = acc;
            __syncthreads();
            if (wid == 0) {
#pragma unroll
                for (int s = 0; s < 3; ++s) {
                    f32x4 r = red[s][lane];
                    acc[0] += r[0]; acc[1] += r[1]; acc[2] += r[2]; acc[3] += r[3];
                }
#pragma unroll
                for (int j = 0; j < 4; ++j) {
                    int row = r0 + kg * 4 + j;
                    if (row < count) {
                        float v = acc[j] + bias;
                        v = v > 0.f ? v : expm1f(v);
                        h1[(size_t)(start + row) * 256 + n0 + ln] = f2bf(v);
                    }
                }
            }
        }
    }

    // ---------------- fan-in: last block of teacher t proceeds ----------------
    __threadfence();                      // release h1 slice (device scope)
    if (threadIdx.x == 0) done_s = atomicAdd(&cnt_g[t], 1);
    __syncthreads();
    if (done_s != 15) return;
    __threadfence();                      // acquire siblings' h1

    // ---------------- L2 + final for the whole teacher ----------------
    short8 bf6[4];
    {
        const float* wr = w6 + ((size_t)t * 12 + (ln < 12 ? ln : 0)) * 128;
#pragma unroll
        for (int kt = 0; kt < 4; ++kt) {
            int kb = kt * 32 + kg * 8;
            bf6[kt] = cvt8(*(const float4*)(wr + kb), *(const float4*)(wr + kb + 4));
        }
    }
    const float bias6 = (ln < 12) ? b6[(size_t)t * 12 + ln] : 0.f;
    const int n0q = wid * 32;             // wave owns 32 L2 output cols

    for (int sc0 = 0; sc0 < count; sc0 += 128) {
        const int lim = min(count - sc0, 128);
        // L2 into LDS: wave's 32 cols for all chunks of this super-chunk
#pragma unroll
        for (int sub = 0; sub < 2; ++sub) {
            const int col = n0q + sub * 16 + ln;
            short8 bfH[8];
            const float* wr = w4 + ((size_t)t * 128 + col) * 256;
#pragma unroll
            for (int k8 = 0; k8 < 8; ++k8) {
                int kb = k8 * 32 + kg * 8;
                bfH[k8] = cvt8(*(const float4*)(wr + kb), *(const float4*)(wr + kb + 4));
            }
            const float biasH = b4[(size_t)t * 128 + col];
            for (int c0 = 0; c0 < lim; c0 += 16) {
                const unsigned short* xr =
                    h1 + (size_t)(start + sc0 + c0 + ln) * 256 + kg * 8;
                f32x4 acc = {0.f, 0.f, 0.f, 0.f};
#pragma unroll
                for (int k8 = 0; k8 < 8; ++k8)
                    acc = __builtin_amdgcn_mfma_f32_16x16x32_bf16(
                        *(const short8*)(xr + k8 * 32), bfH[k8], acc, 0, 0, 0);
#pragma unroll
                for (int j = 0; j < 4; ++j) {
                    int rr = c0 + kg * 4 + j;
                    float v = acc[j] + biasH;
                    v = v > 0.f ? v : expm1f(v);
                    int byte = (rr * 256 + col * 2) ^ ((rr & 7) << 4);
                    *(unsigned short*)(h2b + byte) = f2bf(v);
                }
            }
        }
        __syncthreads();
        // final: wave wid handles chunks wid, wid+4, ...
        for (int c0 = wid * 16; c0 < lim; c0 += 64) {
            f32x4 acc = {0.f, 0.f, 0.f, 0.f};
            int rr = c0 + ln;
#pragma unroll
            for (int kt = 0; kt < 4; ++kt) {
                int byte = (rr * 256 + (kt * 32 + kg * 8) * 2) ^ ((rr & 7) << 4);
                acc = __builtin_amdgcn_mfma_f32_16x16x32_bf16(
                    *(const short8*)(h2b + byte), bf6[kt], acc, 0, 0, 0);
            }
#pragma unroll
            for (int j = 0; j < 4; ++j) {
                int row = sc0 + c0 + kg * 4 + j;
                if (ln < 12 && row < count)
                    out[(size_t)order_g[start + row] * 12 + ln] = tanhf(acc[j] + bias6);
            }
        }
        __syncthreads();                  // LDS reuse for next super-chunk
    }
}

extern "C" void kernel_launch(void* const* d_in, const int* in_sizes, int n_in,
                              void* d_out, int out_size, void* d_ws, size_t ws_size,
                              hipStream_t stream) {
    const float* obs = (const float*)d_in[0];
    const int* tidx  = (const int*)d_in[1];
    const float* w0  = (const float*)d_in[2];
    const float* b0  = (const float*)d_in[3];
    const float* w2  = (const float*)d_in[4];
    const float* b2  = (const float*)d_in[5];
    const float* w4  = (const float*)d_in[6];
    const float* b4  = (const float*)d_in[7];
    const float* w6  = (const float*)d_in[8];
    const float* b6  = (const float*)d_in[9];
    float* out = (float*)d_out;

    // ws: offsets (65 ints) | cnt (64 ints) | order (2048 ints) | h0 | h1.
    // bf16 activations in sorted space; +16 rows slack so tail A-fragment
    // overreads stay in-bounds (slack rows finite garbage, never stored).
    const int ROWS = BATCH + 16;
    char* ws = (char*)d_ws;
    int* offsets = (int*)ws;                              // 65 ints @ 0
    int* cnt     = (int*)(ws + 512);                      // 64 ints
    int* order   = (int*)(ws + 1024);                     // 2048 ints
    unsigned short* h0 = (unsigned short*)(ws + 16384);   // ROWS*512
    unsigned short* h1 = h0 + (size_t)ROWS * 512;         // ROWS*256

    l0_kernel<<<dim3(16, NTEACH), 256, 0, stream>>>(obs, tidx, w0, b0,
                                                    offsets, order, cnt, h0);
    l1f_kernel<<<dim3(16, NTEACH), 256, 0, stream>>>(h0, offsets, order, cnt,
                                                     w2, b2, w4, b4, w6, b6,
                                                     h1, out);
}

// Round 11
// 42.786 us; speedup vs baseline: 3.9840x; 3.9840x over previous
//
#include <hip/hip_runtime.h>

#define BATCH 2048
#define NTEACH 64

typedef __attribute__((ext_vector_type(8))) short short8;
typedef __attribute__((ext_vector_type(4))) float f32x4;

__device__ __forceinline__ unsigned short f2bf(float f) {
    unsigned u = __float_as_uint(f);
    u += 0x7FFFu + ((u >> 16) & 1u);          // round-to-nearest-even
    return (unsigned short)(u >> 16);
}

__device__ __forceinline__ short8 cvt8(float4 a, float4 b) {
    short8 r;
    r[0] = (short)f2bf(a.x); r[1] = (short)f2bf(a.y);
    r[2] = (short)f2bf(a.z); r[3] = (short)f2bf(a.w);
    r[4] = (short)f2bf(b.x); r[5] = (short)f2bf(b.y);
    r[6] = (short)f2bf(b.z); r[7] = (short)f2bf(b.w);
    return r;
}

// Barrier-free per-wave scan (R8-proven): each wave independently computes the
// stable ranking of teacher-t samples. Returns (start, count), wave-uniform.
__device__ __forceinline__ int2 wave_scan(const int* __restrict__ tidx,
                                          int t, int* ord) {
    const int lane = threadIdx.x & 63;
    int base = 0, lt = 0;
#pragma unroll
    for (int r = 0; r < 32; ++r) {
        int i = r * 64 + lane;
        int v = tidx[i];
        bool f = (v == t);
        lt += (v < t) ? 1 : 0;
        unsigned long long b = __ballot(f);
        if (ord && f) {
            int rank = base + __builtin_popcountll(b & ((1ull << lane) - 1ull));
            ord[rank] = i;
        }
        base += __builtin_popcountll(b);
    }
#pragma unroll
    for (int off = 32; off; off >>= 1) lt += __shfl_down(lt, off);
    lt = __shfl(lt, 0);
    return make_int2(lt, base);
}

// ---------- L0: obs(48) -> h0(512) bf16 sorted, gather + elu ----------
// grid (16,64); waves = N2 x M2. Weight loads issued BEFORE the scan (latency
// hidden under it). Block (0,t) publishes offsets/order.
// MFMA 16x16x32 bf16 (verified R2-R9): A row=lane&15, k=(lane>>4)*8+j;
// B col=lane&15; D col=lane&15, row=(lane>>4)*4+j.
__global__ __launch_bounds__(256) void l0_kernel(const float* __restrict__ obs,
                                                 const int* __restrict__ tidx,
                                                 const float* __restrict__ w0,
                                                 const float* __restrict__ b0,
                                                 int* __restrict__ offsets_g,
                                                 int* __restrict__ order_g,
                                                 unsigned short* __restrict__ h0) {
    __shared__ int ord[BATCH];
    const int t = blockIdx.y;
    const int lane = threadIdx.x & 63, wid = threadIdx.x >> 6;
    const int ln = lane & 15, kg = lane >> 4;
    const int nq = wid & 1, mq = wid >> 1;
    const int n0 = blockIdx.x * 32 + nq * 16;

    // issue weight + bias loads first (clamped addresses, masked later)
    const float* wr = w0 + ((size_t)t * 512 + n0 + ln) * 48;
    bool wvalid[2];
    float4 wa[2], wb[2];
#pragma unroll
    for (int kt = 0; kt < 2; ++kt) {
        int kb = kt * 32 + kg * 8;
        wvalid[kt] = kb < 48;
        const float* p = wr + (wvalid[kt] ? kb : 0);
        wa[kt] = *(const float4*)p;
        wb[kt] = *(const float4*)(p + 4);
    }
    const float bias = b0[(size_t)t * 512 + n0 + ln];

    int2 sc = wave_scan(tidx, t, ord);
    const int start = sc.x, count = sc.y;

    if (blockIdx.x == 0) {
        if (threadIdx.x == 0) {
            offsets_g[t] = start;
            if (t == 0) offsets_g[NTEACH] = BATCH;
        }
        for (int i = threadIdx.x; i < count; i += 256) order_g[start + i] = ord[i];
    }
    if (count == 0) return;

    short8 bf[2];
#pragma unroll
    for (int kt = 0; kt < 2; ++kt) {
        short8 z = {0, 0, 0, 0, 0, 0, 0, 0};
        bf[kt] = wvalid[kt] ? cvt8(wa[kt], wb[kt]) : z;
    }

    for (int r0 = mq * 16; r0 < count; r0 += 32) {
        int lr = r0 + ln;
        const float* xr = obs + (size_t)ord[lr < count ? lr : 0] * 48;
        short8 af[2];
#pragma unroll
        for (int kt = 0; kt < 2; ++kt) {
            int kb = kt * 32 + kg * 8;
            short8 f8 = {0, 0, 0, 0, 0, 0, 0, 0};
            if (kb < 48)
                f8 = cvt8(*(const float4*)(xr + kb), *(const float4*)(xr + kb + 4));
            af[kt] = f8;
        }
        f32x4 acc = {0.f, 0.f, 0.f, 0.f};
        acc = __builtin_amdgcn_mfma_f32_16x16x32_bf16(af[0], bf[0], acc, 0, 0, 0);
        acc = __builtin_amdgcn_mfma_f32_16x16x32_bf16(af[1], bf[1], acc, 0, 0, 0);
#pragma unroll
        for (int j = 0; j < 4; ++j) {
            int row = r0 + kg * 4 + j;
            if (row < count) {
                float v = acc[j] + bias;
                v = v > 0.f ? v : expm1f(v);
                h0[(size_t)(start + row) * 512 + n0 + ln] = f2bf(v);
            }
        }
    }
}

// ---------- L1: h0(512) -> h1(256), elu. grid (16,64); waves = K4 ----------
// Block = 16 cols. Per-wave weight burst = 8 dwordx4 in ONE batch (16 VGPR of
// B-frags). w2 read exactly once. 1024 blocks = 4/CU co-resident. LDS 3 KB.
__global__ __launch_bounds__(256) void l1_kernel(const unsigned short* __restrict__ h0,
                                                 const int* __restrict__ offsets_g,
                                                 const float* __restrict__ w2,
                                                 const float* __restrict__ b2,
                                                 unsigned short* __restrict__ h1) {
    __shared__ f32x4 red[3][64];
    const int t = blockIdx.y;
    const int start = offsets_g[t];
    const int count = offsets_g[t + 1] - start;
    if (count == 0) return;
    const int lane = threadIdx.x & 63, wid = threadIdx.x >> 6;
    const int ln = lane & 15, kg = lane >> 4;
    const int n0 = blockIdx.x * 16;
    const int kbase = wid * 128;          // K4 wave split

    short8 bf[4];
    const float* wr = w2 + ((size_t)t * 256 + n0 + ln) * 512 + kbase;
#pragma unroll
    for (int k8 = 0; k8 < 4; ++k8) {
        int kb = k8 * 32 + kg * 8;
        bf[k8] = cvt8(*(const float4*)(wr + kb), *(const float4*)(wr + kb + 4));
    }
    const float bias = b2[(size_t)t * 256 + n0 + ln];

    for (int r0 = 0; r0 < count; r0 += 16) {
        const unsigned short* xr =
            h0 + (size_t)(start + r0 + ln) * 512 + kbase + kg * 8;
        f32x4 acc = {0.f, 0.f, 0.f, 0.f};
#pragma unroll
        for (int k8 = 0; k8 < 4; ++k8)
            acc = __builtin_amdgcn_mfma_f32_16x16x32_bf16(
                *(const short8*)(xr + k8 * 32), bf[k8], acc, 0, 0, 0);
        __syncthreads();
        if (wid > 0) red[wid - 1][lane] = acc;
        __syncthreads();
        if (wid == 0) {
#pragma unroll
            for (int s = 0; s < 3; ++s) {
                f32x4 r = red[s][lane];
                acc[0] += r[0]; acc[1] += r[1]; acc[2] += r[2]; acc[3] += r[3];
            }
#pragma unroll
            for (int j = 0; j < 4; ++j) {
                int row = r0 + kg * 4 + j;
                if (row < count) {
                    float v = acc[j] + bias;
                    v = v > 0.f ? v : expm1f(v);
                    h1[(size_t)(start + row) * 256 + n0 + ln] = f2bf(v);
                }
            }
        }
    }
}

// ---------- L2+final: h1(256) -> h2(128, LDS) -> out(12), tanh --------------
// grid (4,64); 16-row chunk per iteration; h2 XOR-swizzled in LDS. h1 chunk
// fragment loaded ONCE per chunk (reused by both 16-col sub-tiles).
__global__ __launch_bounds__(256) void l2f_kernel(const unsigned short* __restrict__ h1,
                                                  const int* __restrict__ offsets_g,
                                                  const int* __restrict__ order_g,
                                                  const float* __restrict__ w4,
                                                  const float* __restrict__ b4,
                                                  const float* __restrict__ w6,
                                                  const float* __restrict__ b6,
                                                  float* __restrict__ out) {
    __shared__ char h2b[4096];            // 16 rows x 128 cols bf16, swizzled
    const int t = blockIdx.y;
    const int start = offsets_g[t];
    const int count = offsets_g[t + 1] - start;
    if ((int)blockIdx.x * 16 >= count) return;
    const int lane = threadIdx.x & 63, wid = threadIdx.x >> 6;
    const int ln = lane & 15, kg = lane >> 4;
    const int nq = wid;

    short8 bfA[2][8];
    float biasA[2];
#pragma unroll
    for (int sub = 0; sub < 2; ++sub) {
        const float* wr = w4 + ((size_t)t * 128 + nq * 32 + sub * 16 + ln) * 256;
#pragma unroll
        for (int k8 = 0; k8 < 8; ++k8) {
            int kb = k8 * 32 + kg * 8;
            bfA[sub][k8] = cvt8(*(const float4*)(wr + kb), *(const float4*)(wr + kb + 4));
        }
        biasA[sub] = b4[(size_t)t * 128 + nq * 32 + sub * 16 + ln];
    }
    short8 bf6[4];
    float bias6 = 0.f;
    if (wid == 0) {
        const float* wr = w6 + ((size_t)t * 12 + (ln < 12 ? ln : 0)) * 128;
#pragma unroll
        for (int kt = 0; kt < 4; ++kt) {
            int kb = kt * 32 + kg * 8;
            bf6[kt] = cvt8(*(const float4*)(wr + kb), *(const float4*)(wr + kb + 4));
        }
        if (ln < 12) bias6 = b6[(size_t)t * 12 + ln];
    }

    for (int mt = blockIdx.x; mt * 16 < count; mt += gridDim.x) {
        const int gr0 = start + mt * 16;
        // load this chunk's h1 A-fragments ONCE (8 x dwordx4, one batch)
        short8 af[8];
        const unsigned short* xr = h1 + (size_t)(gr0 + ln) * 256 + kg * 8;
#pragma unroll
        for (int k8 = 0; k8 < 8; ++k8) af[k8] = *(const short8*)(xr + k8 * 32);
        // L2: both 16-col sub-tiles from registers
#pragma unroll
        for (int sub = 0; sub < 2; ++sub) {
            f32x4 acc = {0.f, 0.f, 0.f, 0.f};
#pragma unroll
            for (int k8 = 0; k8 < 8; ++k8)
                acc = __builtin_amdgcn_mfma_f32_16x16x32_bf16(af[k8], bfA[sub][k8],
                                                              acc, 0, 0, 0);
            int col = nq * 32 + sub * 16 + ln;
#pragma unroll
            for (int j = 0; j < 4; ++j) {
                int row = kg * 4 + j;             // sample within chunk
                float v = acc[j] + biasA[sub];
                v = v > 0.f ? v : expm1f(v);
                int byte = (row * 256 + col * 2) ^ ((row & 7) << 4);
                *(unsigned short*)(h2b + byte) = f2bf(v);
            }
        }
        __syncthreads();
        // final: wave 0 computes 16 samples x 12 outs, scatter to original rows
        if (wid == 0) {
            f32x4 acc = {0.f, 0.f, 0.f, 0.f};
#pragma unroll
            for (int kt = 0; kt < 4; ++kt) {
                int byte = (ln * 256 + (kt * 32 + kg * 8) * 2) ^ ((ln & 7) << 4);
                acc = __builtin_amdgcn_mfma_f32_16x16x32_bf16(
                    *(const short8*)(h2b + byte), bf6[kt], acc, 0, 0, 0);
            }
#pragma unroll
            for (int j = 0; j < 4; ++j) {
                int row = mt * 16 + kg * 4 + j;
                if (ln < 12 && row < count)
                    out[(size_t)order_g[start + row] * 12 + ln] = tanhf(acc[j] + bias6);
            }
        }
        __syncthreads();
    }
}

extern "C" void kernel_launch(void* const* d_in, const int* in_sizes, int n_in,
                              void* d_out, int out_size, void* d_ws, size_t ws_size,
                              hipStream_t stream) {
    const float* obs = (const float*)d_in[0];
    const int* tidx  = (const int*)d_in[1];
    const float* w0  = (const float*)d_in[2];
    const float* b0  = (const float*)d_in[3];
    const float* w2  = (const float*)d_in[4];
    const float* b2  = (const float*)d_in[5];
    const float* w4  = (const float*)d_in[6];
    const float* b4  = (const float*)d_in[7];
    const float* w6  = (const float*)d_in[8];
    const float* b6  = (const float*)d_in[9];
    float* out = (float*)d_out;

    // ws: offsets (65 ints) | order (2048 ints) | h0 | h1. bf16 activations in
    // sorted space; +16 rows slack so tail A-fragment overreads stay in-bounds
    // (slack rows finite garbage, never stored).
    const int ROWS = BATCH + 16;
    char* ws = (char*)d_ws;
    int* offsets = (int*)ws;                              // 65 ints
    int* order   = (int*)(ws + 1024);                     // 2048 ints
    unsigned short* h0 = (unsigned short*)(ws + 16384);   // ROWS*512
    unsigned short* h1 = h0 + (size_t)ROWS * 512;         // ROWS*256

    l0_kernel<<<dim3(16, NTEACH), 256, 0, stream>>>(obs, tidx, w0, b0,
                                                    offsets, order, h0);
    l1_kernel<<<dim3(16, NTEACH), 256, 0, stream>>>(h0, offsets, w2, b2, h1);
    l2f_kernel<<<dim3(4, NTEACH), 256, 0, stream>>>(h1, offsets, order,
                                                    w4, b4, w6, b6, out);
}